// Round 1
// baseline (3191.540 us; speedup 1.0000x reference)
//
#include <hip/hip_runtime.h>
#include <hip/hip_bf16.h>
#include <math.h>

#define NPTS 100000
#define PAD_ROWS 100032   // 1563 * 64
#define DIM 512
#define GRP 4
#define GD 128
#define K_NBR 16
#define EPS 1e-5f

using bf16x8 = __attribute__((ext_vector_type(8))) short;
using f32x4  = __attribute__((ext_vector_type(4))) float;
using short4v = __attribute__((ext_vector_type(4))) short;

__device__ inline float bf2f(short s) {
    unsigned u = ((unsigned)(unsigned short)s) << 16;
    union { unsigned u; float f; } c; c.u = u; return c.f;
}
__device__ inline short f2bf(float f) {
    union { float f; unsigned u; } c; c.f = f;
    unsigned u = c.u;
    unsigned r = (u + 0x7fffu + ((u >> 16) & 1u)) >> 16;
    return (short)r;
}

// ---------------- weight convert f32 -> bf16 ----------------
__global__ void cvt_kernel(const float* __restrict__ src, short* __restrict__ dst, int n) {
    int i = blockIdx.x * blockDim.x + threadIdx.x;
    int stride = gridDim.x * blockDim.x;
    for (; i < n; i += stride) dst[i] = f2bf(src[i]);
}

// ---------------- LayerNorm (f32 in -> bf16 out), one block of 128 per row ----------------
__global__ void ln_kernel(const float* __restrict__ in, const float* __restrict__ g,
                          const float* __restrict__ b, short* __restrict__ out) {
    int row = blockIdx.x;
    int tid = threadIdx.x; // 128 threads, 4 elems each
    if (row >= NPTS) {
        short4v z; z[0] = 0; z[1] = 0; z[2] = 0; z[3] = 0;
        *(short4v*)(out + (size_t)row * DIM + tid * 4) = z;
        return;
    }
    const float4 x = *(const float4*)(in + (size_t)row * DIM + tid * 4);
    float s  = x.x + x.y + x.z + x.w;
    float sq = x.x * x.x + x.y * x.y + x.z * x.z + x.w * x.w;
    for (int m = 1; m < 64; m <<= 1) {
        s  += __shfl_xor(s, m);
        sq += __shfl_xor(sq, m);
    }
    __shared__ float ss[2], ssq[2];
    int wv = tid >> 6;
    if ((tid & 63) == 0) { ss[wv] = s; ssq[wv] = sq; }
    __syncthreads();
    s = ss[0] + ss[1]; sq = ssq[0] + ssq[1];
    float mu = s * (1.0f / DIM);
    float var = sq * (1.0f / DIM) - mu * mu;
    float rstd = rsqrtf(var + EPS);
    const float4 gg = *(const float4*)(g + tid * 4);
    const float4 bb = *(const float4*)(b + tid * 4);
    short4v o;
    o[0] = f2bf((x.x - mu) * rstd * gg.x + bb.x);
    o[1] = f2bf((x.y - mu) * rstd * gg.y + bb.y);
    o[2] = f2bf((x.z - mu) * rstd * gg.z + bb.z);
    o[3] = f2bf((x.w - mu) * rstd * gg.w + bb.w);
    *(short4v*)(out + (size_t)row * DIM + tid * 4) = o;
}

// ---------------- grouped QKV GEMM: q/k/v[n, g*128+o] = sum_d x[n,g*128+d] * W[g,o,d] ----
__global__ __launch_bounds__(256) void qkv_kernel(
        const short* __restrict__ x,
        const short* __restrict__ wq, const short* __restrict__ wk, const short* __restrict__ wv,
        short* __restrict__ q, short* __restrict__ k, short* __restrict__ v) {
    int t = blockIdx.z;
    const short* W = (t == 0) ? wq : ((t == 1) ? wk : wv);
    short* O = (t == 0) ? q : ((t == 1) ? k : v);
    int tid = threadIdx.x;
    int wave = tid >> 6, lane = tid & 63;
    int r = lane & 15, ks = lane >> 4;
    int rowbase = blockIdx.x * 64 + wave * 16;
    int colbase = blockIdx.y * 64;
    int g = colbase >> 7;
    int lcolbase = colbase & 127;
    const short* Wg = W + g * GD * GD;
    f32x4 acc[4];
    for (int c = 0; c < 4; ++c) for (int e = 0; e < 4; ++e) acc[c][e] = 0.0f;
    for (int k0 = 0; k0 < GD; k0 += 32) {
        bf16x8 a = *(const bf16x8*)(x + (size_t)(rowbase + r) * DIM + g * GD + k0 + ks * 8);
        #pragma unroll
        for (int c = 0; c < 4; ++c) {
            bf16x8 b = *(const bf16x8*)(Wg + (size_t)(lcolbase + c * 16 + r) * GD + k0 + ks * 8);
            acc[c] = __builtin_amdgcn_mfma_f32_16x16x32_bf16(a, b, acc[c], 0, 0, 0);
        }
    }
    #pragma unroll
    for (int c = 0; c < 4; ++c)
        #pragma unroll
        for (int rr = 0; rr < 4; ++rr) {
            int orow = rowbase + ks * 4 + rr;
            int ocol = colbase + c * 16 + r;
            O[(size_t)orow * DIM + ocol] = f2bf(acc[c][rr]);
        }
}

// ---------------- attention: one block per point, one wave per group ----------------
__global__ __launch_bounds__(256) void attn_kernel(
        const short* __restrict__ q, const short* __restrict__ kk, const short* __restrict__ vv,
        const int* __restrict__ nbrs, short* __restrict__ attn) {
    int n = blockIdx.x;
    __shared__ int nb[K_NBR];
    int tid = threadIdx.x;
    if (tid < K_NBR) nb[tid] = nbrs[(size_t)n * K_NBR + tid];
    __syncthreads();
    int g = tid >> 6, lane = tid & 63;
    size_t base = (size_t)n * DIM + g * GD + lane * 2;
    float q0 = bf2f(q[base]), q1 = bf2f(q[base + 1]);
    float sc[K_NBR];
    const float scale = 0.08838834764831845f; // 1/sqrt(128)
    for (int j = 0; j < K_NBR; ++j) {
        size_t kb = (size_t)nb[j] * DIM + g * GD + lane * 2;
        float p = q0 * bf2f(kk[kb]) + q1 * bf2f(kk[kb + 1]);
        for (int m = 1; m < 64; m <<= 1) p += __shfl_xor(p, m);
        sc[j] = p * scale;
    }
    float mx = sc[0];
    for (int j = 1; j < K_NBR; ++j) mx = fmaxf(mx, sc[j]);
    float s = 0.0f;
    for (int j = 0; j < K_NBR; ++j) { sc[j] = expf(sc[j] - mx); s += sc[j]; }
    float inv = 1.0f / s;
    float a0 = 0.0f, a1 = 0.0f;
    for (int j = 0; j < K_NBR; ++j) {
        size_t vb = (size_t)nb[j] * DIM + g * GD + lane * 2;
        float w = sc[j] * inv;
        a0 += w * bf2f(vv[vb]);
        a1 += w * bf2f(vv[vb + 1]);
    }
    attn[base] = f2bf(a0);
    attn[base + 1] = f2bf(a1);
}

// ---------------- out = attn @ Wo.T + bo + features (residual), f32 to d_out ----------
__global__ __launch_bounds__(256) void outproj_kernel(
        const short* __restrict__ attn, const short* __restrict__ wo,
        const float* __restrict__ bo, const float* __restrict__ features,
        float* __restrict__ out) {
    int tid = threadIdx.x;
    int wave = tid >> 6, lane = tid & 63;
    int r = lane & 15, ks = lane >> 4;
    int rowbase = blockIdx.x * 64 + wave * 16;
    int colbase = blockIdx.y * 64;
    f32x4 acc[4];
    for (int c = 0; c < 4; ++c) for (int e = 0; e < 4; ++e) acc[c][e] = 0.0f;
    for (int k0 = 0; k0 < DIM; k0 += 32) {
        bf16x8 a = *(const bf16x8*)(attn + (size_t)(rowbase + r) * DIM + k0 + ks * 8);
        #pragma unroll
        for (int c = 0; c < 4; ++c) {
            bf16x8 b = *(const bf16x8*)(wo + (size_t)(colbase + c * 16 + r) * DIM + k0 + ks * 8);
            acc[c] = __builtin_amdgcn_mfma_f32_16x16x32_bf16(a, b, acc[c], 0, 0, 0);
        }
    }
    #pragma unroll
    for (int c = 0; c < 4; ++c)
        #pragma unroll
        for (int rr = 0; rr < 4; ++rr) {
            int orow = rowbase + ks * 4 + rr;
            int ocol = colbase + c * 16 + r;
            if (orow < NPTS) {
                float val = acc[c][rr] + bo[ocol] + features[(size_t)orow * DIM + ocol];
                out[(size_t)orow * DIM + ocol] = val;
            }
        }
}

// ---------------- FFN1: h = gelu(y @ W1.T + b1), bf16 out, NO=1024 -------------------
__global__ __launch_bounds__(256) void ffn1_kernel(
        const short* __restrict__ y, const short* __restrict__ w1,
        const float* __restrict__ b1, short* __restrict__ h) {
    int tid = threadIdx.x;
    int wave = tid >> 6, lane = tid & 63;
    int r = lane & 15, ks = lane >> 4;
    int rowbase = blockIdx.x * 64 + wave * 16;
    int colbase = blockIdx.y * 64;
    f32x4 acc[4];
    for (int c = 0; c < 4; ++c) for (int e = 0; e < 4; ++e) acc[c][e] = 0.0f;
    for (int k0 = 0; k0 < DIM; k0 += 32) {
        bf16x8 a = *(const bf16x8*)(y + (size_t)(rowbase + r) * DIM + k0 + ks * 8);
        #pragma unroll
        for (int c = 0; c < 4; ++c) {
            bf16x8 b = *(const bf16x8*)(w1 + (size_t)(colbase + c * 16 + r) * DIM + k0 + ks * 8);
            acc[c] = __builtin_amdgcn_mfma_f32_16x16x32_bf16(a, b, acc[c], 0, 0, 0);
        }
    }
    #pragma unroll
    for (int c = 0; c < 4; ++c)
        #pragma unroll
        for (int rr = 0; rr < 4; ++rr) {
            int orow = rowbase + ks * 4 + rr;
            int ocol = colbase + c * 16 + r;
            float xv = acc[c][rr] + b1[ocol];
            float gl = 0.5f * xv * (1.0f + erff(xv * 0.70710678118654752f));
            h[(size_t)orow * (2 * DIM) + ocol] = f2bf(gl);
        }
}

// ---------------- FFN2: d_out = h @ W2.T + b2 + d_out(res2), K=1024 ------------------
__global__ __launch_bounds__(256) void ffn2_kernel(
        const short* __restrict__ h, const short* __restrict__ w2,
        const float* __restrict__ b2, float* __restrict__ out) {
    int tid = threadIdx.x;
    int wave = tid >> 6, lane = tid & 63;
    int r = lane & 15, ks = lane >> 4;
    int rowbase = blockIdx.x * 64 + wave * 16;
    int colbase = blockIdx.y * 64;
    f32x4 acc[4];
    for (int c = 0; c < 4; ++c) for (int e = 0; e < 4; ++e) acc[c][e] = 0.0f;
    for (int k0 = 0; k0 < 2 * DIM; k0 += 32) {
        bf16x8 a = *(const bf16x8*)(h + (size_t)(rowbase + r) * (2 * DIM) + k0 + ks * 8);
        #pragma unroll
        for (int c = 0; c < 4; ++c) {
            bf16x8 b = *(const bf16x8*)(w2 + (size_t)(colbase + c * 16 + r) * (2 * DIM) + k0 + ks * 8);
            acc[c] = __builtin_amdgcn_mfma_f32_16x16x32_bf16(a, b, acc[c], 0, 0, 0);
        }
    }
    #pragma unroll
    for (int c = 0; c < 4; ++c)
        #pragma unroll
        for (int rr = 0; rr < 4; ++rr) {
            int orow = rowbase + ks * 4 + rr;
            int ocol = colbase + c * 16 + r;
            if (orow < NPTS) {
                size_t idx = (size_t)orow * DIM + ocol;
                out[idx] = acc[c][rr] + b2[ocol] + out[idx];
            }
        }
}

extern "C" void kernel_launch(void* const* d_in, const int* in_sizes, int n_in,
                              void* d_out, int out_size, void* d_ws, size_t ws_size,
                              hipStream_t stream) {
    const float* features = (const float*)d_in[0];
    // d_in[1] = coords (unused by reference)
    const int*   neighbors = (const int*)d_in[2];
    const float* Wq = (const float*)d_in[3];
    const float* Wk = (const float*)d_in[4];
    const float* Wv = (const float*)d_in[5];
    const float* Wo = (const float*)d_in[6];
    const float* bo = (const float*)d_in[7];
    const float* ln1_g = (const float*)d_in[8];
    const float* ln1_b = (const float*)d_in[9];
    const float* ln2_g = (const float*)d_in[10];
    const float* ln2_b = (const float*)d_in[11];
    const float* W1 = (const float*)d_in[12];
    const float* b1 = (const float*)d_in[13];
    const float* W2 = (const float*)d_in[14];
    const float* b2 = (const float*)d_in[15];
    float* out = (float*)d_out;

    size_t slotElems = (size_t)PAD_ROWS * DIM;
    short* s0 = (short*)d_ws;            // x -> attn
    short* s1 = s0 + slotElems;          // q -> y(ln2)
    short* s2 = s1 + slotElems;          // k -> h (low half)
    short* s3 = s2 + slotElems;          // v -> h (high half)
    short* wq_b = s3 + slotElems;
    short* wk_b = wq_b + GRP * GD * GD;
    short* wv_b = wk_b + GRP * GD * GD;
    short* wo_b = wv_b + GRP * GD * GD;
    short* w1_b = wo_b + DIM * DIM;
    short* w2_b = w1_b + 2 * DIM * DIM;

    cvt_kernel<<<128, 256, 0, stream>>>(Wq, wq_b, GRP * GD * GD);
    cvt_kernel<<<128, 256, 0, stream>>>(Wk, wk_b, GRP * GD * GD);
    cvt_kernel<<<128, 256, 0, stream>>>(Wv, wv_b, GRP * GD * GD);
    cvt_kernel<<<256, 256, 0, stream>>>(Wo, wo_b, DIM * DIM);
    cvt_kernel<<<256, 256, 0, stream>>>(W1, w1_b, 2 * DIM * DIM);
    cvt_kernel<<<256, 256, 0, stream>>>(W2, w2_b, 2 * DIM * DIM);

    // LN1: features -> x (bf16), zero-padded rows
    ln_kernel<<<PAD_ROWS, 128, 0, stream>>>(features, ln1_g, ln1_b, s0);

    // grouped QKV
    qkv_kernel<<<dim3(PAD_ROWS / 64, 8, 3), 256, 0, stream>>>(s0, wq_b, wk_b, wv_b, s1, s2, s3);

    // attention -> attn in s0
    attn_kernel<<<NPTS, 256, 0, stream>>>(s1, s2, s3, neighbors, s0);

    // out = attn @ Wo.T + bo + features  (f32, in d_out)
    outproj_kernel<<<dim3(PAD_ROWS / 64, 8), 256, 0, stream>>>(s0, wo_b, bo, features, out);

    // LN2: d_out -> y (bf16) in s1
    ln_kernel<<<PAD_ROWS, 128, 0, stream>>>(out, ln2_g, ln2_b, s1);

    // FFN1: h = gelu(y @ W1.T + b1) -> s2 (P x 1024 bf16)
    ffn1_kernel<<<dim3(PAD_ROWS / 64, 16), 256, 0, stream>>>(s1, w1_b, b1, s2);

    // FFN2: d_out = h @ W2.T + b2 + d_out
    ffn2_kernel<<<dim3(PAD_ROWS / 64, 8), 256, 0, stream>>>(s2, w2_b, b2, out);
}

// Round 2
// 1480.147 us; speedup vs baseline: 2.1562x; 2.1562x over previous
//
#include <hip/hip_runtime.h>
#include <hip/hip_bf16.h>
#include <math.h>

#define NPTS 100000
#define PAD_ROWS 100096   // 782 * 128
#define DIM 512
#define GRP 4
#define GD 128
#define K_NBR 16
#define EPS 1e-5f

using bf16x8 = __attribute__((ext_vector_type(8))) short;
using f32x4  = __attribute__((ext_vector_type(4))) float;
using short4v = __attribute__((ext_vector_type(4))) short;

__device__ inline float bf2f(short s) {
    unsigned u = ((unsigned)(unsigned short)s) << 16;
    union { unsigned u; float f; } c; c.u = u; return c.f;
}
__device__ inline short f2bf(float f) {
    union { float f; unsigned u; } c; c.f = f;
    unsigned u = c.u;
    unsigned r = (u + 0x7fffu + ((u >> 16) & 1u)) >> 16;
    return (short)r;
}

__device__ __forceinline__ void gload_lds16(short* lds, const short* g) {
    __builtin_amdgcn_global_load_lds(
        (const __attribute__((address_space(1))) unsigned int*)g,
        (__attribute__((address_space(3))) unsigned int*)lds, 16, 0, 0);
}

// ---------------- weight convert f32 -> bf16 ----------------
__global__ void cvt_kernel(const float* __restrict__ src, short* __restrict__ dst, int n) {
    int i = blockIdx.x * blockDim.x + threadIdx.x;
    int stride = gridDim.x * blockDim.x;
    for (; i < n; i += stride) dst[i] = f2bf(src[i]);
}

// ---------------- LayerNorm (f32 in -> bf16 out) ----------------
__global__ void ln_kernel(const float* __restrict__ in, const float* __restrict__ g,
                          const float* __restrict__ b, short* __restrict__ out) {
    int row = blockIdx.x;
    int tid = threadIdx.x; // 128 threads, 4 elems each
    if (row >= NPTS) {
        short4v z; z[0] = 0; z[1] = 0; z[2] = 0; z[3] = 0;
        *(short4v*)(out + (size_t)row * DIM + tid * 4) = z;
        return;
    }
    const float4 x = *(const float4*)(in + (size_t)row * DIM + tid * 4);
    float s  = x.x + x.y + x.z + x.w;
    float sq = x.x * x.x + x.y * x.y + x.z * x.z + x.w * x.w;
    for (int m = 1; m < 64; m <<= 1) {
        s  += __shfl_xor(s, m);
        sq += __shfl_xor(sq, m);
    }
    __shared__ float ss[2], ssq[2];
    int wv = tid >> 6;
    if ((tid & 63) == 0) { ss[wv] = s; ssq[wv] = sq; }
    __syncthreads();
    s = ss[0] + ss[1]; sq = ssq[0] + ssq[1];
    float mu = s * (1.0f / DIM);
    float var = sq * (1.0f / DIM) - mu * mu;
    float rstd = rsqrtf(var + EPS);
    const float4 gg = *(const float4*)(g + tid * 4);
    const float4 bb = *(const float4*)(b + tid * 4);
    short4v o;
    o[0] = f2bf((x.x - mu) * rstd * gg.x + bb.x);
    o[1] = f2bf((x.y - mu) * rstd * gg.y + bb.y);
    o[2] = f2bf((x.z - mu) * rstd * gg.z + bb.z);
    o[3] = f2bf((x.w - mu) * rstd * gg.w + bb.w);
    *(short4v*)(out + (size_t)row * DIM + tid * 4) = o;
}

// ---------------- shared 128x128 GEMM core (BK=32, 4 waves 2x2, m97 structure) --------
// C[128][128] += A[128 rows, k..] * B[128 cols(as rows), k..]^T
template<int NK>
__device__ __forceinline__ void gemm_tile(
        const short* __restrict__ aBase, int as_,   // &A[rowbase][k0], row stride
        const short* __restrict__ bBase, int bs_,   // &B[colbase][k0], row stride
        short* As, short* Bs, f32x4 (&acc)[4][4]) {
    int tid = threadIdx.x;
    int lane = tid & 63, wave = tid >> 6;
    int wr = wave >> 1, wc = wave & 1;
    int r = lane & 15, ks = lane >> 4;
    int ldRow = tid >> 2;            // 0..63
    int ldCol = (tid & 3) * 8;       // element col within BK=32
    for (int kt = 0; kt < NK; ++kt) {
        __syncthreads();
        const short* aS = aBase + kt * 32;
        const short* bS = bBase + kt * 32;
        gload_lds16(As + (ldRow)      * 32 + ldCol, aS + (size_t)(ldRow)      * as_ + ldCol);
        gload_lds16(As + (ldRow + 64) * 32 + ldCol, aS + (size_t)(ldRow + 64) * as_ + ldCol);
        gload_lds16(Bs + (ldRow)      * 32 + ldCol, bS + (size_t)(ldRow)      * bs_ + ldCol);
        gload_lds16(Bs + (ldRow + 64) * 32 + ldCol, bS + (size_t)(ldRow + 64) * bs_ + ldCol);
        __syncthreads();
        bf16x8 a[4];
        #pragma unroll
        for (int m = 0; m < 4; ++m)
            a[m] = *(const bf16x8*)(As + (wr * 64 + m * 16 + r) * 32 + ks * 8);
        #pragma unroll
        for (int n = 0; n < 4; ++n) {
            bf16x8 b = *(const bf16x8*)(Bs + (wc * 64 + n * 16 + r) * 32 + ks * 8);
            #pragma unroll
            for (int m = 0; m < 4; ++m)
                acc[m][n] = __builtin_amdgcn_mfma_f32_16x16x32_bf16(a[m], b, acc[m][n], 0, 0, 0);
        }
    }
}

// ---------------- fused grouped QKV: per block (rowblock, group), loop q/k/v ----------
__global__ __launch_bounds__(256) void qkv_kernel(
        const short* __restrict__ x,
        const short* __restrict__ wq, const short* __restrict__ wk, const short* __restrict__ wv,
        short* __restrict__ q, short* __restrict__ k, short* __restrict__ v) {
    __shared__ short As[128 * 32], Bs[128 * 32];
    int nwg = gridDim.x;             // 782*4 = 3128, %8==0
    int bid = blockIdx.x;
    int tile = (bid & 7) * (nwg >> 3) + (bid >> 3);
    int rb = tile >> 2, g = tile & 3;
    int rowbase = rb * 128;
    int tid = threadIdx.x;
    int lane = tid & 63, wave = tid >> 6;
    int wr = wave >> 1, wc = wave & 1;
    int r = lane & 15, ks = lane >> 4;
    const short* Ws[3] = {wq, wk, wv};
    short* Os[3] = {q, k, v};
    #pragma unroll
    for (int t = 0; t < 3; ++t) {
        f32x4 acc[4][4];
        #pragma unroll
        for (int m = 0; m < 4; ++m)
            #pragma unroll
            for (int n = 0; n < 4; ++n)
                #pragma unroll
                for (int e = 0; e < 4; ++e) acc[m][n][e] = 0.0f;
        gemm_tile<4>(x + (size_t)rowbase * DIM + g * GD, DIM,
                     Ws[t] + g * GD * GD, GD, As, Bs, acc);
        short* O = Os[t];
        #pragma unroll
        for (int m = 0; m < 4; ++m)
            #pragma unroll
            for (int n = 0; n < 4; ++n)
                #pragma unroll
                for (int rr = 0; rr < 4; ++rr) {
                    int orow = rowbase + wr * 64 + m * 16 + ks * 4 + rr;
                    int ocol = g * GD + wc * 64 + n * 16 + r;
                    O[(size_t)orow * DIM + ocol] = f2bf(acc[m][n][rr]);
                }
    }
}

// ---------------- attention: one block per point, one wave per group ----------------
__global__ __launch_bounds__(256) void attn_kernel(
        const short* __restrict__ q, const short* __restrict__ kk, const short* __restrict__ vv,
        const int* __restrict__ nbrs, short* __restrict__ attn) {
    int n = blockIdx.x;
    __shared__ int nb[K_NBR];
    int tid = threadIdx.x;
    if (tid < K_NBR) nb[tid] = nbrs[(size_t)n * K_NBR + tid];
    __syncthreads();
    int g = tid >> 6, lane = tid & 63;
    size_t base = (size_t)n * DIM + g * GD + lane * 2;
    float q0 = bf2f(q[base]), q1 = bf2f(q[base + 1]);
    float sc[K_NBR];
    const float scale = 0.08838834764831845f; // 1/sqrt(128)
    for (int j = 0; j < K_NBR; ++j) {
        size_t kb = (size_t)nb[j] * DIM + g * GD + lane * 2;
        float p = q0 * bf2f(kk[kb]) + q1 * bf2f(kk[kb + 1]);
        for (int m = 1; m < 64; m <<= 1) p += __shfl_xor(p, m);
        sc[j] = p * scale;
    }
    float mx = sc[0];
    for (int j = 1; j < K_NBR; ++j) mx = fmaxf(mx, sc[j]);
    float s = 0.0f;
    for (int j = 0; j < K_NBR; ++j) { sc[j] = expf(sc[j] - mx); s += sc[j]; }
    float inv = 1.0f / s;
    float a0 = 0.0f, a1 = 0.0f;
    for (int j = 0; j < K_NBR; ++j) {
        size_t vb = (size_t)nb[j] * DIM + g * GD + lane * 2;
        float w = sc[j] * inv;
        a0 += w * bf2f(vv[vb]);
        a1 += w * bf2f(vv[vb + 1]);
    }
    attn[base] = f2bf(a0);
    attn[base + 1] = f2bf(a1);
}

// ---------------- out = attn @ Wo.T + bo + features (residual) -> f32 d_out ----------
__global__ __launch_bounds__(256) void outproj_kernel(
        const short* __restrict__ attn, const short* __restrict__ wo,
        const float* __restrict__ bo, const float* __restrict__ features,
        float* __restrict__ out) {
    __shared__ short As[128 * 32], Bs[128 * 32];
    int nwg = gridDim.x;             // 782*4
    int bid = blockIdx.x;
    int tile = (bid & 7) * (nwg >> 3) + (bid >> 3);
    int rb = tile >> 2, cb = tile & 3;
    int rowbase = rb * 128, colbase = cb * 128;
    int tid = threadIdx.x;
    int lane = tid & 63, wave = tid >> 6;
    int wr = wave >> 1, wc = wave & 1;
    int r = lane & 15, ks = lane >> 4;
    f32x4 acc[4][4];
    #pragma unroll
    for (int m = 0; m < 4; ++m)
        #pragma unroll
        for (int n = 0; n < 4; ++n)
            #pragma unroll
            for (int e = 0; e < 4; ++e) acc[m][n][e] = 0.0f;
    gemm_tile<16>(attn + (size_t)rowbase * DIM, DIM,
                  wo + (size_t)colbase * DIM, DIM, As, Bs, acc);
    #pragma unroll
    for (int m = 0; m < 4; ++m)
        #pragma unroll
        for (int n = 0; n < 4; ++n)
            #pragma unroll
            for (int rr = 0; rr < 4; ++rr) {
                int orow = rowbase + wr * 64 + m * 16 + ks * 4 + rr;
                int ocol = colbase + wc * 64 + n * 16 + r;
                if (orow < NPTS) {
                    out[(size_t)orow * DIM + ocol] =
                        acc[m][n][rr] + bo[ocol] + features[(size_t)orow * DIM + ocol];
                }
            }
}

// ---------------- FFN1: h = gelu(y @ W1.T + b1), bf16 out, N=1024 --------------------
__global__ __launch_bounds__(256) void ffn1_kernel(
        const short* __restrict__ y, const short* __restrict__ w1,
        const float* __restrict__ b1, short* __restrict__ h) {
    __shared__ short As[128 * 32], Bs[128 * 32];
    int nwg = gridDim.x;             // 782*8
    int bid = blockIdx.x;
    int tile = (bid & 7) * (nwg >> 3) + (bid >> 3);
    int rb = tile >> 3, cb = tile & 7;
    int rowbase = rb * 128, colbase = cb * 128;
    int tid = threadIdx.x;
    int lane = tid & 63, wave = tid >> 6;
    int wr = wave >> 1, wc = wave & 1;
    int r = lane & 15, ks = lane >> 4;
    f32x4 acc[4][4];
    #pragma unroll
    for (int m = 0; m < 4; ++m)
        #pragma unroll
        for (int n = 0; n < 4; ++n)
            #pragma unroll
            for (int e = 0; e < 4; ++e) acc[m][n][e] = 0.0f;
    gemm_tile<16>(y + (size_t)rowbase * DIM, DIM,
                  w1 + (size_t)colbase * DIM, DIM, As, Bs, acc);
    #pragma unroll
    for (int m = 0; m < 4; ++m)
        #pragma unroll
        for (int n = 0; n < 4; ++n)
            #pragma unroll
            for (int rr = 0; rr < 4; ++rr) {
                int orow = rowbase + wr * 64 + m * 16 + ks * 4 + rr;
                int ocol = colbase + wc * 64 + n * 16 + r;
                float xv = acc[m][n][rr] + b1[ocol];
                float gl = 0.5f * xv * (1.0f + erff(xv * 0.70710678118654752f));
                h[(size_t)orow * (2 * DIM) + ocol] = f2bf(gl);
            }
}

// ---------------- FFN2: d_out = h @ W2.T + b2 + d_out(res2), K=1024 ------------------
__global__ __launch_bounds__(256) void ffn2_kernel(
        const short* __restrict__ h, const short* __restrict__ w2,
        const float* __restrict__ b2, float* __restrict__ out) {
    __shared__ short As[128 * 32], Bs[128 * 32];
    int nwg = gridDim.x;             // 782*4
    int bid = blockIdx.x;
    int tile = (bid & 7) * (nwg >> 3) + (bid >> 3);
    int rb = tile >> 2, cb = tile & 3;
    int rowbase = rb * 128, colbase = cb * 128;
    int tid = threadIdx.x;
    int lane = tid & 63, wave = tid >> 6;
    int wr = wave >> 1, wc = wave & 1;
    int r = lane & 15, ks = lane >> 4;
    f32x4 acc[4][4];
    #pragma unroll
    for (int m = 0; m < 4; ++m)
        #pragma unroll
        for (int n = 0; n < 4; ++n)
            #pragma unroll
            for (int e = 0; e < 4; ++e) acc[m][n][e] = 0.0f;
    gemm_tile<32>(h + (size_t)rowbase * (2 * DIM), 2 * DIM,
                  w2 + (size_t)colbase * (2 * DIM), 2 * DIM, As, Bs, acc);
    #pragma unroll
    for (int m = 0; m < 4; ++m)
        #pragma unroll
        for (int n = 0; n < 4; ++n)
            #pragma unroll
            for (int rr = 0; rr < 4; ++rr) {
                int orow = rowbase + wr * 64 + m * 16 + ks * 4 + rr;
                int ocol = colbase + wc * 64 + n * 16 + r;
                if (orow < NPTS) {
                    size_t idx = (size_t)orow * DIM + ocol;
                    out[idx] = acc[m][n][rr] + b2[ocol] + out[idx];
                }
            }
}

extern "C" void kernel_launch(void* const* d_in, const int* in_sizes, int n_in,
                              void* d_out, int out_size, void* d_ws, size_t ws_size,
                              hipStream_t stream) {
    const float* features = (const float*)d_in[0];
    const int*   neighbors = (const int*)d_in[2];
    const float* Wq = (const float*)d_in[3];
    const float* Wk = (const float*)d_in[4];
    const float* Wv = (const float*)d_in[5];
    const float* Wo = (const float*)d_in[6];
    const float* bo = (const float*)d_in[7];
    const float* ln1_g = (const float*)d_in[8];
    const float* ln1_b = (const float*)d_in[9];
    const float* ln2_g = (const float*)d_in[10];
    const float* ln2_b = (const float*)d_in[11];
    const float* W1 = (const float*)d_in[12];
    const float* b1 = (const float*)d_in[13];
    const float* W2 = (const float*)d_in[14];
    const float* b2 = (const float*)d_in[15];
    float* out = (float*)d_out;

    size_t slotElems = (size_t)PAD_ROWS * DIM;
    short* s0 = (short*)d_ws;            // x -> attn
    short* s1 = s0 + slotElems;          // q -> y(ln2)
    short* s2 = s1 + slotElems;          // k -> h (low half)
    short* s3 = s2 + slotElems;          // v -> h (high half)
    short* wq_b = s3 + slotElems;
    short* wk_b = wq_b + GRP * GD * GD;
    short* wv_b = wk_b + GRP * GD * GD;
    short* wo_b = wv_b + GRP * GD * GD;
    short* w1_b = wo_b + DIM * DIM;
    short* w2_b = w1_b + 2 * DIM * DIM;

    cvt_kernel<<<128, 256, 0, stream>>>(Wq, wq_b, GRP * GD * GD);
    cvt_kernel<<<128, 256, 0, stream>>>(Wk, wk_b, GRP * GD * GD);
    cvt_kernel<<<128, 256, 0, stream>>>(Wv, wv_b, GRP * GD * GD);
    cvt_kernel<<<256, 256, 0, stream>>>(Wo, wo_b, DIM * DIM);
    cvt_kernel<<<256, 256, 0, stream>>>(W1, w1_b, 2 * DIM * DIM);
    cvt_kernel<<<256, 256, 0, stream>>>(W2, w2_b, 2 * DIM * DIM);

    // LN1: features -> x (bf16), zero-padded rows
    ln_kernel<<<PAD_ROWS, 128, 0, stream>>>(features, ln1_g, ln1_b, s0);

    // grouped QKV (fused q/k/v loop per block)
    qkv_kernel<<<(PAD_ROWS / 128) * 4, 256, 0, stream>>>(s0, wq_b, wk_b, wv_b, s1, s2, s3);

    // attention -> attn in s0
    attn_kernel<<<NPTS, 256, 0, stream>>>(s1, s2, s3, neighbors, s0);

    // out = attn @ Wo.T + bo + features  (f32, in d_out)
    outproj_kernel<<<(PAD_ROWS / 128) * 4, 256, 0, stream>>>(s0, wo_b, bo, features, out);

    // LN2: d_out -> y (bf16) in s1
    ln_kernel<<<PAD_ROWS, 128, 0, stream>>>(out, ln2_g, ln2_b, s1);

    // FFN1: h = gelu(y @ W1.T + b1) -> s2:s3 (P x 1024 bf16)
    ffn1_kernel<<<(PAD_ROWS / 128) * 8, 256, 0, stream>>>(s1, w1_b, b1, s2);

    // FFN2: d_out = h @ W2.T + b2 + d_out
    ffn2_kernel<<<(PAD_ROWS / 128) * 4, 256, 0, stream>>>(s2, w2_b, b2, out);
}